// Round 11
// baseline (183.368 us; speedup 1.0000x reference)
//
#include <hip/hip_runtime.h>

typedef unsigned short u16;
typedef unsigned int u32;
typedef short bf16x8 __attribute__((ext_vector_type(8)));
typedef short bf16x4 __attribute__((ext_vector_type(4)));
typedef float f32x4 __attribute__((ext_vector_type(4)));
typedef u32 u32x2 __attribute__((ext_vector_type(2)));

#define LOG2E 1.4426950408889634f
#define QSCALE (0.125f * LOG2E)   // folded into Q at QKV epilogue

__device__ __forceinline__ u16 f2b(float f) {
  u32 u = __builtin_bit_cast(u32, f);
  u32 r = (u + 0x7FFFu + ((u >> 16) & 1u)) >> 16;
  return (u16)r;
}

// 8 consecutive fp32 -> bf16x8
__device__ __forceinline__ bf16x8 cvt8(const float* p) {
  const f32x4 a = *(const f32x4*)p;
  const f32x4 b = *(const f32x4*)(p + 4);
  bf16x8 r = { (short)f2b(a[0]), (short)f2b(a[1]), (short)f2b(a[2]),
               (short)f2b(a[3]), (short)f2b(b[0]), (short)f2b(b[1]),
               (short)f2b(b[2]), (short)f2b(b[3]) };
  return r;
}

// async global->LDS, 16B per lane; lds dest must be wave-uniform base.
__device__ __forceinline__ void gl_lds16(const u16* g, u16* l) {
  __builtin_amdgcn_global_load_lds(
      (const __attribute__((address_space(1))) u32*)(const void*)g,
      (__attribute__((address_space(3))) u32*)(void*)l, 16, 0, 0);
}

// ---------------------------------------------------------------------------
// fp32 -> bf16 one-shot converts (x+Wq/Wk/Wv into d_out scratch, dead until
// gemm_out writes the real output).
// ---------------------------------------------------------------------------
__global__ __launch_bounds__(256) void convert_qw_kernel(
    const float* __restrict__ x, const float* __restrict__ wq,
    const float* __restrict__ wk, const float* __restrict__ wv,
    u16* __restrict__ xb, u16* __restrict__ wb) {
  const int i = blockIdx.x * 256 + threadIdx.x;
  if (i >= 917504) return;  // 524288 (x) + 3*131072 (w)
  const float* src;
  u16* dst;
  size_t off;
  if (i < 524288) {
    src = x; dst = xb; off = (size_t)i * 8;
  } else {
    const int j = i - 524288;
    const int mat = j >> 17, r = j & 131071;
    src = (mat == 0) ? wq : ((mat == 1) ? wk : wv);
    dst = wb + (size_t)mat * 1048576u;
    off = (size_t)r * 8;
  }
  *(bf16x8*)(dst + off) = cvt8(src + off);
}

// Wo fp32 -> bf16 into kb region (dead after flash); launched after flash.
__global__ __launch_bounds__(256) void convert_wo_kernel(
    const float* __restrict__ wo, u16* __restrict__ wob) {
  const int i = blockIdx.x * 256 + threadIdx.x;
  if (i >= 131072) return;
  const size_t off = (size_t)i * 8;
  *(bf16x8*)(wob + off) = cvt8(wo + off);
}

// ---------------------------------------------------------------------------
// NT GEMM core v4 (counted-vmcnt, T3/T4; R7/R8-verified): C[128x128] +=
// A*W^T, K=1024, BK=32, THREE LDS buffers, TWO stages in flight. Per K-step:
//   s_waitcnt vmcnt(4); s_barrier; stage(t+2); ds_read + 16 MFMA.
// Load latency cover = 2 full K-steps. Chunk-XOR swizzle verified R3.
// ---------------------------------------------------------------------------
__device__ __forceinline__ void gemm_core4(const u16* A, const u16* W,
                                           int m0, int n0, int tid,
                                           u16* As, u16* Bs,  // each 3*4096
                                           f32x4 (&acc)[4][4]) {
  const int lane = tid & 63, wave = tid >> 6;
  const int wr = wave >> 1, wc = wave & 1;
  const int l15 = lane & 15, quad = lane >> 4;

  const int srow = wave * 16 + (lane >> 2);                  // + i*64
  const int csrc =
      (((lane & 3) ^ ((lane >> 2) & 3) ^ ((lane >> 4) & 3)) << 3);  // u16
  const u16* ga = A + (size_t)(m0 + srow) * 1024 + csrc;
  const u16* gw = W + (size_t)(n0 + srow) * 1024 + csrc;
  const int lo = wave * 16 * 32;                             // u16, + i*64*32

  const int rswz = (l15 & 3) ^ ((l15 >> 2) & 3);
  const int aoff = (wr * 64 + l15) * 32 + ((quad ^ rswz) << 3);
  const int boff = (wc * 64 + l15) * 32 + ((quad ^ rswz) << 3);

  auto stage = [&](int k0, int db) {
    u16* la = As + db * 4096 + lo;
    u16* lb = Bs + db * 4096 + lo;
    gl_lds16(ga + k0, la);
    gl_lds16(ga + k0 + (size_t)64 * 1024, la + 64 * 32);
    gl_lds16(gw + k0, lb);
    gl_lds16(gw + k0 + (size_t)64 * 1024, lb + 64 * 32);
  };

  stage(0, 0);
  stage(32, 1);
  int db = 0, dbn = 2;  // dbn: buffer for k0+64
  for (int k0 = 0; k0 < 1024; k0 += 32) {
    if (k0 == 992) {
      asm volatile("s_waitcnt vmcnt(0)" ::: "memory");
    } else {
      asm volatile("s_waitcnt vmcnt(4)" ::: "memory");
    }
    __builtin_amdgcn_s_barrier();
    __builtin_amdgcn_sched_barrier(0);
    if (k0 + 64 < 1024) stage(k0 + 64, dbn);
    const u16* ar = As + db * 4096 + aoff;
    const u16* br = Bs + db * 4096 + boff;
    bf16x8 af[4], bfr[4];
#pragma unroll
    for (int i = 0; i < 4; ++i) af[i] = *(const bf16x8*)(ar + i * 16 * 32);
#pragma unroll
    for (int i = 0; i < 4; ++i) bfr[i] = *(const bf16x8*)(br + i * 16 * 32);
#pragma unroll
    for (int mt = 0; mt < 4; ++mt)
#pragma unroll
      for (int nt = 0; nt < 4; ++nt)
        acc[mt][nt] = __builtin_amdgcn_mfma_f32_16x16x32_bf16(
            af[mt], bfr[nt], acc[mt][nt], 0, 0, 0);
    db = (db == 2) ? 0 : db + 1;
    dbn = (dbn == 2) ? 0 : dbn + 1;
  }
}

// ---------------------------------------------------------------------------
// Fused QKV projection (bf16 in, bf16 out). Q pre-scaled by 0.125*log2e.
// V transposed: vt[(b*1024+e)*2048 + s].
// NEW (R11): XCD capacity clustering. 1-D grid 768; xcd = g&7 owns panels
// {3*xcd .. 3*xcd+2} x all 32 m-blocks -> per-XCD W working set 768 KB
// (L2-resident, was 6 MB thrash) and x slices shared 3-ways by co-resident
// panel triples. j = g>>3: m = j/3, pl = j%3 (m-major: the 3 panels of one
// m-slice are dispatch-adjacent -> x slice read once from L3, 2 L2 hits).
// Epilogue: R10 LDS-repack coalesced stores (verified).
// ---------------------------------------------------------------------------
__global__ __launch_bounds__(256, 3) void gemm_qkv_kernel(
    const u16* __restrict__ xb, const u16* __restrict__ wb,
    u16* __restrict__ qo, u16* __restrict__ ko, u16* __restrict__ vt) {
  __shared__ __align__(16) u16 As[3 * 4096];
  __shared__ __align__(16) u16 Bs[3 * 4096];
  const int tid = threadIdx.x;
  const int g = blockIdx.x;
  const int xcd = g & 7;
  const int j = g >> 3;            // 0..95
  const int mblk = j / 3;          // 0..31
  const int pl = j - mblk * 3;     // 0..2
  const int panel = xcd * 3 + pl;  // 0..23, bijective
  const int m0 = mblk * 128;
  const int mat = panel >> 3;
  const int n0 = (panel & 7) * 128;
  const u16* W = wb + (size_t)mat * 1048576u;

  f32x4 acc[4][4] = {};
  gemm_core4(xb, W, m0, n0, tid, As, Bs, acc);

  const int lane = tid & 63, wave = tid >> 6;
  const int wr = wave >> 1, wc = wave & 1;
  const int l15 = lane & 15, quad = lane >> 4;

  __syncthreads();  // all waves' K-loop LDS reads done; As/Bs reusable
  // per-wave repack tile: 64 x 72 u16 (stride 144B, 16B-aligned rows)
  u16* T = ((wave < 2) ? As : Bs) + (wave & 1) * 4608;
  const int rr = lane >> 3;          // 0..7
  const int cc = (lane & 7) * 8;     // 0..56, 16B-aligned

  if (mat < 2) {
    u16* out = (mat == 0) ? qo : ko;
    const float sc = (mat == 0) ? QSCALE : 1.0f;
    // T[s][e]: s = mt*16+quad*4+r, e = nt*16+l15
#pragma unroll
    for (int mt = 0; mt < 4; ++mt)
#pragma unroll
      for (int nt = 0; nt < 4; ++nt)
#pragma unroll
        for (int r = 0; r < 4; ++r)
          T[(mt * 16 + quad * 4 + r) * 72 + nt * 16 + l15] =
              f2b(acc[mt][nt][r] * sc);
    asm volatile("s_waitcnt lgkmcnt(0)" ::: "memory");  // same-wave tile
    u16* outp = out + (size_t)(m0 + wr * 64) * 1024 + n0 + wc * 64;
#pragma unroll
    for (int i = 0; i < 8; ++i) {
      const int row = i * 8 + rr;
      const bf16x8 v = *(const bf16x8*)&T[row * 72 + cc];
      *(bf16x8*)&outp[(size_t)row * 1024 + cc] = v;
    }
  } else {
    // V: transpose during repack. T[e][s]: e = nt*16+l15, s = mt*16+quad*4+r
    const int b = m0 >> 11;                 // block fully within one batch
    const int sblk = (m0 & 2047) + wr * 64;
#pragma unroll
    for (int mt = 0; mt < 4; ++mt)
#pragma unroll
      for (int nt = 0; nt < 4; ++nt) {
        bf16x4 pk = { (short)f2b(acc[mt][nt][0]), (short)f2b(acc[mt][nt][1]),
                      (short)f2b(acc[mt][nt][2]), (short)f2b(acc[mt][nt][3]) };
        *(bf16x4*)&T[(nt * 16 + l15) * 72 + mt * 16 + quad * 4] = pk;
      }
    asm volatile("s_waitcnt lgkmcnt(0)" ::: "memory");
    u16* vtp = vt + (size_t)(b * 1024 + n0 + wc * 64) * 2048 + sblk;
#pragma unroll
    for (int i = 0; i < 8; ++i) {
      const int erow = i * 8 + rr;
      const bf16x8 v = *(const bf16x8*)&T[erow * 72 + cc];
      *(bf16x8*)&vtp[(size_t)erow * 2048 + cc] = v;
    }
  }
}

// ---------------------------------------------------------------------------
// Output projection (R9 core FROZEN): counted-vmcnt pipeline, 128x64 tiles,
// BK=64, 3 LDS buffers (72 KB, 2 blocks/CU), vmcnt(6).
// NEW (R11): XCD clustering. 1-D grid 512; xcd = g&7 owns n-panels
// {2*xcd, 2*xcd+1} x all 32 m-blocks -> Wo working set 256 KB L2-resident;
// ctx slices shared 2-ways by dispatch-adjacent panel pairs.
// ---------------------------------------------------------------------------
__global__ __launch_bounds__(256, 2) void gemm_out_kernel(
    const u16* __restrict__ ctx, const u16* __restrict__ wob,
    const float* __restrict__ bo, float* __restrict__ out) {
  __shared__ __align__(16) u16 As[3 * 8192];  // 48 KB
  __shared__ __align__(16) u16 Bs[3 * 4096];  // 24 KB
  const int tid = threadIdx.x;
  const int g = blockIdx.x;
  const int xcd = g & 7;
  const int j = g >> 3;                 // 0..63
  const int m0 = (j >> 1) * 128;
  const int n0 = (xcd * 2 + (j & 1)) * 64;
  const int lane = tid & 63, wave = tid >> 6;
  const int wr = wave >> 1, wc = wave & 1;
  const int l15 = lane & 15, quad = lane >> 4;

  const int srow = tid >> 3;                                 // + i*32
  const int csrc = (((tid & 7) ^ ((tid >> 3) & 7)) << 3);    // u16 offset
  const u16* ga = ctx + (size_t)(m0 + srow) * 1024 + csrc;
  const u16* gw = wob + (size_t)(n0 + srow) * 1024 + csrc;
  const int lo = wave * 512;                                 // u16
  const int swz = l15 & 7;

  auto stage = [&](int k0, int db) {
    u16* la = As + db * 8192 + lo;
    u16* lb = Bs + db * 4096 + lo;
#pragma unroll
    for (int i = 0; i < 4; ++i)
      gl_lds16(ga + (size_t)(i * 32) * 1024 + k0, la + i * 2048);
#pragma unroll
    for (int i = 0; i < 2; ++i)
      gl_lds16(gw + (size_t)(i * 32) * 1024 + k0, lb + i * 2048);
  };

  f32x4 acc[4][2] = {};
  stage(0, 0);
  stage(64, 1);
  int db = 0, dbn = 2;
  for (int k0 = 0; k0 < 1024; k0 += 64) {
    if (k0 == 960) {
      asm volatile("s_waitcnt vmcnt(0)" ::: "memory");
    } else {
      asm volatile("s_waitcnt vmcnt(6)" ::: "memory");
    }
    __builtin_amdgcn_s_barrier();
    __builtin_amdgcn_sched_barrier(0);
    if (k0 + 128 < 1024) stage(k0 + 128, dbn);
    const u16* ab = As + db * 8192;
    const u16* bb = Bs + db * 4096;
    bf16x8 af[4][2], bfr[2][2];
#pragma unroll
    for (int mt = 0; mt < 4; ++mt)
#pragma unroll
      for (int kk = 0; kk < 2; ++kk)
        af[mt][kk] = *(const bf16x8*)(ab + (wr * 64 + mt * 16 + l15) * 64 +
                                      ((((kk << 2) | quad) ^ swz) << 3));
#pragma unroll
    for (int nt = 0; nt < 2; ++nt)
#pragma unroll
      for (int kk = 0; kk < 2; ++kk)
        bfr[nt][kk] = *(const bf16x8*)(bb + (wc * 32 + nt * 16 + l15) * 64 +
                                       ((((kk << 2) | quad) ^ swz) << 3));
#pragma unroll
    for (int kk = 0; kk < 2; ++kk)
#pragma unroll
      for (int mt = 0; mt < 4; ++mt)
#pragma unroll
        for (int nt = 0; nt < 2; ++nt)
          acc[mt][nt] = __builtin_amdgcn_mfma_f32_16x16x32_bf16(
              af[mt][kk], bfr[nt][kk], acc[mt][nt], 0, 0, 0);
    db = (db == 2) ? 0 : db + 1;
    dbn = (dbn == 2) ? 0 : dbn + 1;
  }

#pragma unroll
  for (int nt = 0; nt < 2; ++nt) {
    const int gc = n0 + wc * 32 + nt * 16 + l15;
    const float bv = bo[gc];
#pragma unroll
    for (int mt = 0; mt < 4; ++mt) {
      const int gr = m0 + wr * 64 + mt * 16 + quad * 4;
#pragma unroll
      for (int r = 0; r < 4; ++r)
        out[(size_t)(gr + r) * 1024 + gc] = acc[mt][nt][r] + bv;
    }
  }
}

// ---------------------------------------------------------------------------
// Flash v6 (R3/R5/R6/R8-verified, ~56us): XCD capacity clustering,
// 1-barrier/iter staging pipeline, VALU-diet softmax. FROZEN.
// ctx aliases q: per-wave q-slices read at start == slices written at end.
// ---------------------------------------------------------------------------
__global__ __launch_bounds__(256, 4) void flash_kernel(
    const u16* q, const u16* __restrict__ k,
    const u16* __restrict__ vt, u16* ctx) {
  __shared__ __align__(16) u16 Ks[2][4096];       // [kv 64][d 64] swizzled
  __shared__ __align__(16) u16 Vs[2][4096];       // [d 64][kv 64] swizzled
  __shared__ __align__(16) u16 plds_all[4][1024]; // [wave][16 q][64 kv] swz

  const int tid = threadIdx.x;
  const int wave = tid >> 6, lane = tid & 63;
  const int l15 = lane & 15, quad = lane >> 4;

  // ---- XCD-clustered block mapping ----
  const int g = blockIdx.x;
  const int xcd = g & 7;
  const int s = g >> 3;            // 0..127 within XCD
  const int bh_local = s >> 5;     // 0..3
  const int c = s & 31;
  const int qv = (bh_local & 1) ? (31 - c) : c;   // snake: CU sums = 66
  const int q0b = qv * 64;
  const int ntiles = qv + 1;       // block-uniform
  const int bh = xcd + 8 * bh_local;
  const int b = bh >> 4, h = bh & 15;
  const int m = q0b + wave * 16 + l15;            // q-row this lane owns

  const u16* qrow = q + ((size_t)(b * 2048 + m) * 1024 + h * 64);
  const bf16x8 qf0 = *(const bf16x8*)(qrow + quad * 8);
  const bf16x8 qf1 = *(const bf16x8*)(qrow + 32 + quad * 8);

  const int sr = wave * 16 + (lane >> 3);                    // + i*8
  const int csrc = (((lane & 7) ^ ((lane >> 3) & 7)) << 3);  // u16 offset
  const u16* kg = k + (size_t)(b * 2048) * 1024 + h * 64;
  const u16* vg = vt + (size_t)(b * 1024 + h * 64) * 2048;
  u16* plds = plds_all[wave];
  const int swz = (l15 & 7);                      // read-side row XOR

  f32x4 o[4] = {};
  float m_run = -INFINITY, l_lane = 0.0f;

  // prologue: stage tile 0 into buf 0
#pragma unroll
  for (int i = 0; i < 2; ++i) {
    const int r = sr + i * 8;
    gl_lds16(kg + (size_t)r * 1024 + csrc, &Ks[0][wave * 1024 + i * 512]);
    gl_lds16(vg + (size_t)r * 2048 + csrc, &Vs[0][wave * 1024 + i * 512]);
  }
  __syncthreads();  // drains vmcnt(0) -> tile 0 resident

  int buf = 0;
  for (int t = 0; t < ntiles; ++t) {
    const int n0 = t * 64;
    // issue next-tile staging (overlaps with compute; drained at barrier)
    if (t + 1 < ntiles) {
      const int n1 = n0 + 64;
      const int nb = buf ^ 1;
#pragma unroll
      for (int i = 0; i < 2; ++i) {
        const int r = sr + i * 8;
        gl_lds16(kg + (size_t)(n1 + r) * 1024 + csrc,
                 &Ks[nb][wave * 1024 + i * 512]);
        gl_lds16(vg + (size_t)r * 2048 + n1 + csrc,
                 &Vs[nb][wave * 1024 + i * 512]);
      }
    }

    // ---- QK^T: st[s4] covers kv = n0 + s4*16 + quad*4 + r, q = l15 ----
    f32x4 st[4];
#pragma unroll
    for (int s4 = 0; s4 < 4; ++s4) {
      const u16* kr = &Ks[buf][(s4 * 16 + l15) * 64];
      const bf16x8 kf0 = *(const bf16x8*)(kr + ((quad ^ swz) << 3));
      const bf16x8 kf1 = *(const bf16x8*)(kr + (((4 | quad) ^ swz) << 3));
      f32x4 a = {};
      a = __builtin_amdgcn_mfma_f32_16x16x32_bf16(kf0, qf0, a, 0, 0, 0);
      a = __builtin_amdgcn_mfma_f32_16x16x32_bf16(kf1, qf1, a, 0, 0, 0);
      st[s4] = a;
    }

    // ---- softmax (scores already in log2 domain via pre-scaled Q) ----
    float s[16];
#pragma unroll
    for (int s4 = 0; s4 < 4; ++s4)
#pragma unroll
      for (int r = 0; r < 4; ++r) s[s4 * 4 + r] = st[s4][r];
    if (t == ntiles - 1) {  // diagonal tile: the only one needing the mask
#pragma unroll
      for (int s4 = 0; s4 < 4; ++s4)
#pragma unroll
        for (int r = 0; r < 4; ++r) {
          const int kv = n0 + s4 * 16 + quad * 4 + r;
          if (kv > m) s[s4 * 4 + r] = -INFINITY;
        }
    }
    float t8[8], t4[4];
#pragma unroll
    for (int i = 0; i < 8; ++i) t8[i] = fmaxf(s[i], s[i + 8]);
#pragma unroll
    for (int i = 0; i < 4; ++i) t4[i] = fmaxf(t8[i], t8[i + 4]);
    float mx = fmaxf(fmaxf(t4[0], t4[1]), fmaxf(t4[2], t4[3]));
    mx = fmaxf(mx, __shfl_xor(mx, 16));
    mx = fmaxf(mx, __shfl_xor(mx, 32));

    float mbase;
    if (__all(mx <= m_run + 8.0f)) {
      mbase = m_run;                     // defer: P bounded by 2^8, bf16-safe
    } else {
      mbase = fmaxf(m_run, mx);
      const float alpha = exp2f(m_run - mbase);  // 0 on first tile
      l_lane *= alpha;
#pragma unroll
      for (int dt = 0; dt < 4; ++dt) o[dt] *= alpha;
      m_run = mbase;
    }

    float p[16];
#pragma unroll
    for (int i = 0; i < 16; ++i) p[i] = exp2f(s[i] - mbase);
    float u8[8], u4[4];
#pragma unroll
    for (int i = 0; i < 8; ++i) u8[i] = p[i] + p[i + 8];
#pragma unroll
    for (int i = 0; i < 4; ++i) u4[i] = u8[i] + u8[i + 4];
    l_lane += (u4[0] + u4[1]) + (u4[2] + u4[3]);  // lane-local

    // ---- P -> LDS, stride 64 + chunk XOR swizzle; cvt_pk packing ----
#pragma unroll
    for (int s4 = 0; s4 < 4; ++s4) {
      u32 c0, c1;
      asm("v_cvt_pk_bf16_f32 %0, %1, %2"
          : "=v"(c0) : "v"(p[s4 * 4 + 0]), "v"(p[s4 * 4 + 1]));
      asm("v_cvt_pk_bf16_f32 %0, %1, %2"
          : "=v"(c1) : "v"(p[s4 * 4 + 2]), "v"(p[s4 * 4 + 3]));
      const int wchunk = ((s4 * 2 + (quad >> 1)) ^ swz) << 3;
      u32x2 w = { c0, c1 };
      *(u32x2*)&plds[l15 * 64 + wchunk + ((quad & 1) << 2)] = w;
    }
    asm volatile("s_waitcnt lgkmcnt(0)" ::: "memory");

    // ---- PV: o[dt] row = d = dt*16 + quad*4 + r, col = q = l15 ----
#pragma unroll
    for (int ks = 0; ks < 2; ++ks) {
      const bf16x8 pf =
          *(const bf16x8*)&plds[l15 * 64 + (((ks * 4 + quad) ^ swz) << 3)];
#pragma unroll
      for (int dt = 0; dt < 4; ++dt) {
        const u16* vr = &Vs[buf][(dt * 16 + l15) * 64];
        const bf16x8 vf =
            *(const bf16x8*)(vr + ((((ks << 2) | quad) ^ swz) << 3));
        o[dt] = __builtin_amdgcn_mfma_f32_16x16x32_bf16(vf, pf, o[dt], 0, 0, 0);
      }
    }

    __syncthreads();  // drains vmcnt(0): next tile staged; buf safe to reuse
    buf ^= 1;
  }

  float l = l_lane;
  l += __shfl_xor(l, 16);
  l += __shfl_xor(l, 32);
  const float inv = 1.0f / l;
  u16* crow = ctx + ((size_t)(b * 2048 + m) * 1024 + h * 64);
#pragma unroll
  for (int dt = 0; dt < 4; ++dt) {
    bf16x4 ov = { (short)f2b(o[dt][0] * inv), (short)f2b(o[dt][1] * inv),
                  (short)f2b(o[dt][2] * inv), (short)f2b(o[dt][3] * inv) };
    *(bf16x4*)&crow[dt * 16 + quad * 4] = ov;
  }
}

// ---------------------------------------------------------------------------
extern "C" void kernel_launch(void* const* d_in, const int* in_sizes, int n_in,
                              void* d_out, int out_size, void* d_ws,
                              size_t ws_size, hipStream_t stream) {
  // Interface (R9-verified): inputs fp32 in dict order, output fp32.
  const float* x  = (const float*)d_in[0];
  const float* wq = (const float*)d_in[1];
  const float* wk = (const float*)d_in[2];
  const float* wv = (const float*)d_in[3];
  const float* wo = (const float*)d_in[4];
  const float* bo = (const float*)d_in[5];
  float* out = (float*)d_out;

  // ws (bf16 elems): qb [0,4M) (aliased as ctx), kb [4M,8M), vt [8M,12M).
  // kb is dead after flash -> holds Wo in bf16 for gemm_out.
  u16* qb = (u16*)d_ws;
  u16* kb = qb + 4194304u;
  u16* vt = kb + 4194304u;
  u16* ctx = qb;
  u16* wob = kb;

  // d_out doubles as pre-converted-operand scratch until gemm_out runs:
  // xb [0, 8MiB) = x in bf16; wb [8, 14MiB) = Wq|Wk|Wv in bf16.
  u16* xb = (u16*)d_out;
  u16* wb = xb + 4194304u;

  convert_qw_kernel<<<3584, 256, 0, stream>>>(x, wq, wk, wv, xb, wb);
  gemm_qkv_kernel<<<768, 256, 0, stream>>>(xb, wb, qb, kb, vt);
  flash_kernel<<<1024, 256, 0, stream>>>(qb, kb, vt, ctx);
  convert_wo_kernel<<<512, 256, 0, stream>>>(wo, wob);
  gemm_out_kernel<<<512, 256, 0, stream>>>(ctx, wob, bo, out);
}

// Round 12
// 180.094 us; speedup vs baseline: 1.0182x; 1.0182x over previous
//
#include <hip/hip_runtime.h>

typedef unsigned short u16;
typedef unsigned int u32;
typedef short bf16x8 __attribute__((ext_vector_type(8)));
typedef short bf16x4 __attribute__((ext_vector_type(4)));
typedef float f32x4 __attribute__((ext_vector_type(4)));
typedef u32 u32x2 __attribute__((ext_vector_type(2)));

#define LOG2E 1.4426950408889634f
#define QSCALE (0.125f * LOG2E)   // folded into Q at QKV epilogue

__device__ __forceinline__ u16 f2b(float f) {
  u32 u = __builtin_bit_cast(u32, f);
  u32 r = (u + 0x7FFFu + ((u >> 16) & 1u)) >> 16;
  return (u16)r;
}

// 8 consecutive fp32 -> bf16x8
__device__ __forceinline__ bf16x8 cvt8(const float* p) {
  const f32x4 a = *(const f32x4*)p;
  const f32x4 b = *(const f32x4*)(p + 4);
  bf16x8 r = { (short)f2b(a[0]), (short)f2b(a[1]), (short)f2b(a[2]),
               (short)f2b(a[3]), (short)f2b(b[0]), (short)f2b(b[1]),
               (short)f2b(b[2]), (short)f2b(b[3]) };
  return r;
}

// async global->LDS, 16B per lane; lds dest must be wave-uniform base.
__device__ __forceinline__ void gl_lds16(const u16* g, u16* l) {
  __builtin_amdgcn_global_load_lds(
      (const __attribute__((address_space(1))) u32*)(const void*)g,
      (__attribute__((address_space(3))) u32*)(void*)l, 16, 0, 0);
}

// ---------------------------------------------------------------------------
// fp32 -> bf16 one-shot converts (x+Wq/Wk/Wv into d_out scratch, dead until
// gemm_out writes the real output).
// ---------------------------------------------------------------------------
__global__ __launch_bounds__(256) void convert_qw_kernel(
    const float* __restrict__ x, const float* __restrict__ wq,
    const float* __restrict__ wk, const float* __restrict__ wv,
    u16* __restrict__ xb, u16* __restrict__ wb) {
  const int i = blockIdx.x * 256 + threadIdx.x;
  if (i >= 917504) return;  // 524288 (x) + 3*131072 (w)
  const float* src;
  u16* dst;
  size_t off;
  if (i < 524288) {
    src = x; dst = xb; off = (size_t)i * 8;
  } else {
    const int j = i - 524288;
    const int mat = j >> 17, r = j & 131071;
    src = (mat == 0) ? wq : ((mat == 1) ? wk : wv);
    dst = wb + (size_t)mat * 1048576u;
    off = (size_t)r * 8;
  }
  *(bf16x8*)(dst + off) = cvt8(src + off);
}

// Wo fp32 -> bf16 into kb region (dead after flash); launched after flash.
__global__ __launch_bounds__(256) void convert_wo_kernel(
    const float* __restrict__ wo, u16* __restrict__ wob) {
  const int i = blockIdx.x * 256 + threadIdx.x;
  if (i >= 131072) return;
  const size_t off = (size_t)i * 8;
  *(bf16x8*)(wob + off) = cvt8(wo + off);
}

// ---------------------------------------------------------------------------
// NT GEMM core v4 (counted-vmcnt, T3/T4; R7/R8-verified): C[128x128] +=
// A*W^T, K=1024, BK=32, THREE LDS buffers, TWO stages in flight. Per K-step:
//   s_waitcnt vmcnt(4); s_barrier; stage(t+2); ds_read + 16 MFMA.
// Load latency cover = 2 full K-steps. Chunk-XOR swizzle verified R3.
// ---------------------------------------------------------------------------
__device__ __forceinline__ void gemm_core4(const u16* A, const u16* W,
                                           int m0, int n0, int tid,
                                           u16* As, u16* Bs,  // each 3*4096
                                           f32x4 (&acc)[4][4]) {
  const int lane = tid & 63, wave = tid >> 6;
  const int wr = wave >> 1, wc = wave & 1;
  const int l15 = lane & 15, quad = lane >> 4;

  const int srow = wave * 16 + (lane >> 2);                  // + i*64
  const int csrc =
      (((lane & 3) ^ ((lane >> 2) & 3) ^ ((lane >> 4) & 3)) << 3);  // u16
  const u16* ga = A + (size_t)(m0 + srow) * 1024 + csrc;
  const u16* gw = W + (size_t)(n0 + srow) * 1024 + csrc;
  const int lo = wave * 16 * 32;                             // u16, + i*64*32

  const int rswz = (l15 & 3) ^ ((l15 >> 2) & 3);
  const int aoff = (wr * 64 + l15) * 32 + ((quad ^ rswz) << 3);
  const int boff = (wc * 64 + l15) * 32 + ((quad ^ rswz) << 3);

  auto stage = [&](int k0, int db) {
    u16* la = As + db * 4096 + lo;
    u16* lb = Bs + db * 4096 + lo;
    gl_lds16(ga + k0, la);
    gl_lds16(ga + k0 + (size_t)64 * 1024, la + 64 * 32);
    gl_lds16(gw + k0, lb);
    gl_lds16(gw + k0 + (size_t)64 * 1024, lb + 64 * 32);
  };

  stage(0, 0);
  stage(32, 1);
  int db = 0, dbn = 2;  // dbn: buffer for k0+64
  for (int k0 = 0; k0 < 1024; k0 += 32) {
    if (k0 == 992) {
      asm volatile("s_waitcnt vmcnt(0)" ::: "memory");
    } else {
      asm volatile("s_waitcnt vmcnt(4)" ::: "memory");
    }
    __builtin_amdgcn_s_barrier();
    __builtin_amdgcn_sched_barrier(0);
    if (k0 + 64 < 1024) stage(k0 + 64, dbn);
    const u16* ar = As + db * 4096 + aoff;
    const u16* br = Bs + db * 4096 + boff;
    bf16x8 af[4], bfr[4];
#pragma unroll
    for (int i = 0; i < 4; ++i) af[i] = *(const bf16x8*)(ar + i * 16 * 32);
#pragma unroll
    for (int i = 0; i < 4; ++i) bfr[i] = *(const bf16x8*)(br + i * 16 * 32);
#pragma unroll
    for (int mt = 0; mt < 4; ++mt)
#pragma unroll
      for (int nt = 0; nt < 4; ++nt)
        acc[mt][nt] = __builtin_amdgcn_mfma_f32_16x16x32_bf16(
            af[mt], bfr[nt], acc[mt][nt], 0, 0, 0);
    db = (db == 2) ? 0 : db + 1;
    dbn = (dbn == 2) ? 0 : dbn + 1;
  }
}

// ---------------------------------------------------------------------------
// Fused QKV projection (bf16 in, bf16 out). Q pre-scaled by 0.125*log2e.
// V transposed: vt[(b*1024+e)*2048 + s]. blockIdx.y: [0..7]=Q, [8..15]=K,
// [16..23]=V. LDS 48KB -> 3 blocks/CU. R10 epilogue LDS-repack (verified:
// coalesced dwordx4 stores, -6.5us).
// ---------------------------------------------------------------------------
__global__ __launch_bounds__(256, 3) void gemm_qkv_kernel(
    const u16* __restrict__ xb, const u16* __restrict__ wb,
    u16* __restrict__ qo, u16* __restrict__ ko, u16* __restrict__ vt) {
  __shared__ __align__(16) u16 As[3 * 4096];
  __shared__ __align__(16) u16 Bs[3 * 4096];
  const int tid = threadIdx.x;
  const int m0 = blockIdx.x * 128;
  const int mat = blockIdx.y >> 3;
  const int n0 = (blockIdx.y & 7) * 128;
  const u16* W = wb + (size_t)mat * 1048576u;

  f32x4 acc[4][4] = {};
  gemm_core4(xb, W, m0, n0, tid, As, Bs, acc);

  const int lane = tid & 63, wave = tid >> 6;
  const int wr = wave >> 1, wc = wave & 1;
  const int l15 = lane & 15, quad = lane >> 4;

  __syncthreads();  // all waves' K-loop LDS reads done; As/Bs reusable
  // per-wave repack tile: 64 x 72 u16 (stride 144B, 16B-aligned rows)
  u16* T = ((wave < 2) ? As : Bs) + (wave & 1) * 4608;
  const int rr = lane >> 3;          // 0..7
  const int cc = (lane & 7) * 8;     // 0..56, 16B-aligned

  if (mat < 2) {
    u16* out = (mat == 0) ? qo : ko;
    const float sc = (mat == 0) ? QSCALE : 1.0f;
    // T[s][e]: s = mt*16+quad*4+r, e = nt*16+l15
#pragma unroll
    for (int mt = 0; mt < 4; ++mt)
#pragma unroll
      for (int nt = 0; nt < 4; ++nt)
#pragma unroll
        for (int r = 0; r < 4; ++r)
          T[(mt * 16 + quad * 4 + r) * 72 + nt * 16 + l15] =
              f2b(acc[mt][nt][r] * sc);
    asm volatile("s_waitcnt lgkmcnt(0)" ::: "memory");  // same-wave tile
    u16* outp = out + (size_t)(m0 + wr * 64) * 1024 + n0 + wc * 64;
#pragma unroll
    for (int i = 0; i < 8; ++i) {
      const int row = i * 8 + rr;
      const bf16x8 v = *(const bf16x8*)&T[row * 72 + cc];
      *(bf16x8*)&outp[(size_t)row * 1024 + cc] = v;
    }
  } else {
    // V: transpose during repack. T[e][s]: e = nt*16+l15, s = mt*16+quad*4+r
    const int b = m0 >> 11;                 // block fully within one batch
    const int sblk = (m0 & 2047) + wr * 64;
#pragma unroll
    for (int mt = 0; mt < 4; ++mt)
#pragma unroll
      for (int nt = 0; nt < 4; ++nt) {
        bf16x4 pk = { (short)f2b(acc[mt][nt][0]), (short)f2b(acc[mt][nt][1]),
                      (short)f2b(acc[mt][nt][2]), (short)f2b(acc[mt][nt][3]) };
        *(bf16x4*)&T[(nt * 16 + l15) * 72 + mt * 16 + quad * 4] = pk;
      }
    asm volatile("s_waitcnt lgkmcnt(0)" ::: "memory");
    u16* vtp = vt + (size_t)(b * 1024 + n0 + wc * 64) * 2048 + sblk;
#pragma unroll
    for (int i = 0; i < 8; ++i) {
      const int erow = i * 8 + rr;
      const bf16x8 v = *(const bf16x8*)&T[erow * 72 + cc];
      *(bf16x8*)&vtp[(size_t)erow * 2048 + cc] = v;
    }
  }
}

// ---------------------------------------------------------------------------
// Output projection (R9/R10 FROZEN): counted-vmcnt pipeline, 128x64 tiles,
// BK=64 -> 16 MFMA per K-step, 16 steps. 3 LDS buffers (72 KB, 2 blocks/CU),
// 2 stages in flight, 6 VMEM/stage -> vmcnt(6). Chunk-XOR swizzle.
// Grid dim3(32,16) (R11 XCD remap reverted: null-to-negative).
// ---------------------------------------------------------------------------
__global__ __launch_bounds__(256, 2) void gemm_out_kernel(
    const u16* __restrict__ ctx, const u16* __restrict__ wob,
    const float* __restrict__ bo, float* __restrict__ out) {
  __shared__ __align__(16) u16 As[3 * 8192];  // 48 KB
  __shared__ __align__(16) u16 Bs[3 * 4096];  // 24 KB
  const int tid = threadIdx.x;
  const int m0 = blockIdx.x * 128;
  const int n0 = blockIdx.y * 64;
  const int lane = tid & 63, wave = tid >> 6;
  const int wr = wave >> 1, wc = wave & 1;
  const int l15 = lane & 15, quad = lane >> 4;

  const int srow = tid >> 3;                                 // + i*32
  const int csrc = (((tid & 7) ^ ((tid >> 3) & 7)) << 3);    // u16 offset
  const u16* ga = ctx + (size_t)(m0 + srow) * 1024 + csrc;
  const u16* gw = wob + (size_t)(n0 + srow) * 1024 + csrc;
  const int lo = wave * 512;                                 // u16
  const int swz = l15 & 7;

  auto stage = [&](int k0, int db) {
    u16* la = As + db * 8192 + lo;
    u16* lb = Bs + db * 4096 + lo;
#pragma unroll
    for (int i = 0; i < 4; ++i)
      gl_lds16(ga + (size_t)(i * 32) * 1024 + k0, la + i * 2048);
#pragma unroll
    for (int i = 0; i < 2; ++i)
      gl_lds16(gw + (size_t)(i * 32) * 1024 + k0, lb + i * 2048);
  };

  f32x4 acc[4][2] = {};
  stage(0, 0);
  stage(64, 1);
  int db = 0, dbn = 2;
  for (int k0 = 0; k0 < 1024; k0 += 64) {
    if (k0 == 960) {
      asm volatile("s_waitcnt vmcnt(0)" ::: "memory");
    } else {
      asm volatile("s_waitcnt vmcnt(6)" ::: "memory");
    }
    __builtin_amdgcn_s_barrier();
    __builtin_amdgcn_sched_barrier(0);
    if (k0 + 128 < 1024) stage(k0 + 128, dbn);
    const u16* ab = As + db * 8192;
    const u16* bb = Bs + db * 4096;
    bf16x8 af[4][2], bfr[2][2];
#pragma unroll
    for (int mt = 0; mt < 4; ++mt)
#pragma unroll
      for (int kk = 0; kk < 2; ++kk)
        af[mt][kk] = *(const bf16x8*)(ab + (wr * 64 + mt * 16 + l15) * 64 +
                                      ((((kk << 2) | quad) ^ swz) << 3));
#pragma unroll
    for (int nt = 0; nt < 2; ++nt)
#pragma unroll
      for (int kk = 0; kk < 2; ++kk)
        bfr[nt][kk] = *(const bf16x8*)(bb + (wc * 32 + nt * 16 + l15) * 64 +
                                       ((((kk << 2) | quad) ^ swz) << 3));
#pragma unroll
    for (int kk = 0; kk < 2; ++kk)
#pragma unroll
      for (int mt = 0; mt < 4; ++mt)
#pragma unroll
        for (int nt = 0; nt < 2; ++nt)
          acc[mt][nt] = __builtin_amdgcn_mfma_f32_16x16x32_bf16(
              af[mt][kk], bfr[nt][kk], acc[mt][nt], 0, 0, 0);
    db = (db == 2) ? 0 : db + 1;
    dbn = (dbn == 2) ? 0 : dbn + 1;
  }

#pragma unroll
  for (int nt = 0; nt < 2; ++nt) {
    const int gc = n0 + wc * 32 + nt * 16 + l15;
    const float bv = bo[gc];
#pragma unroll
    for (int mt = 0; mt < 4; ++mt) {
      const int gr = m0 + wr * 64 + mt * 16 + quad * 4;
#pragma unroll
      for (int r = 0; r < 4; ++r)
        out[(size_t)(gr + r) * 1024 + gc] = acc[mt][nt][r] + bv;
    }
  }
}

// ---------------------------------------------------------------------------
// Flash v6 + T5 setprio (the single new variable this round): wrap the QK
// and PV MFMA clusters in s_setprio(1)/(0). Mechanism (m191): pays when
// co-resident waves are at different phases (here: softmax VALU chains vs
// MFMA clusters between barriers). Pure scheduling hint - bit-identical.
// Everything else is the R3/R5/R6/R8/R10-verified v6 (~56us).
// ctx aliases q: per-wave q-slices read at start == slices written at end.
// ---------------------------------------------------------------------------
__global__ __launch_bounds__(256, 4) void flash_kernel(
    const u16* q, const u16* __restrict__ k,
    const u16* __restrict__ vt, u16* ctx) {
  __shared__ __align__(16) u16 Ks[2][4096];       // [kv 64][d 64] swizzled
  __shared__ __align__(16) u16 Vs[2][4096];       // [d 64][kv 64] swizzled
  __shared__ __align__(16) u16 plds_all[4][1024]; // [wave][16 q][64 kv] swz

  const int tid = threadIdx.x;
  const int wave = tid >> 6, lane = tid & 63;
  const int l15 = lane & 15, quad = lane >> 4;

  // ---- XCD-clustered block mapping ----
  const int g = blockIdx.x;
  const int xcd = g & 7;
  const int s = g >> 3;            // 0..127 within XCD
  const int bh_local = s >> 5;     // 0..3
  const int c = s & 31;
  const int qv = (bh_local & 1) ? (31 - c) : c;   // snake: CU sums = 66
  const int q0b = qv * 64;
  const int ntiles = qv + 1;       // block-uniform
  const int bh = xcd + 8 * bh_local;
  const int b = bh >> 4, h = bh & 15;
  const int m = q0b + wave * 16 + l15;            // q-row this lane owns

  const u16* qrow = q + ((size_t)(b * 2048 + m) * 1024 + h * 64);
  const bf16x8 qf0 = *(const bf16x8*)(qrow + quad * 8);
  const bf16x8 qf1 = *(const bf16x8*)(qrow + 32 + quad * 8);

  const int sr = wave * 16 + (lane >> 3);                    // + i*8
  const int csrc = (((lane & 7) ^ ((lane >> 3) & 7)) << 3);  // u16 offset
  const u16* kg = k + (size_t)(b * 2048) * 1024 + h * 64;
  const u16* vg = vt + (size_t)(b * 1024 + h * 64) * 2048;
  u16* plds = plds_all[wave];
  const int swz = (l15 & 7);                      // read-side row XOR

  f32x4 o[4] = {};
  float m_run = -INFINITY, l_lane = 0.0f;

  // prologue: stage tile 0 into buf 0
#pragma unroll
  for (int i = 0; i < 2; ++i) {
    const int r = sr + i * 8;
    gl_lds16(kg + (size_t)r * 1024 + csrc, &Ks[0][wave * 1024 + i * 512]);
    gl_lds16(vg + (size_t)r * 2048 + csrc, &Vs[0][wave * 1024 + i * 512]);
  }
  __syncthreads();  // drains vmcnt(0) -> tile 0 resident

  int buf = 0;
  for (int t = 0; t < ntiles; ++t) {
    const int n0 = t * 64;
    // issue next-tile staging (overlaps with compute; drained at barrier)
    if (t + 1 < ntiles) {
      const int n1 = n0 + 64;
      const int nb = buf ^ 1;
#pragma unroll
      for (int i = 0; i < 2; ++i) {
        const int r = sr + i * 8;
        gl_lds16(kg + (size_t)(n1 + r) * 1024 + csrc,
                 &Ks[nb][wave * 1024 + i * 512]);
        gl_lds16(vg + (size_t)r * 2048 + n1 + csrc,
                 &Vs[nb][wave * 1024 + i * 512]);
      }
    }

    // ---- QK^T: st[s4] covers kv = n0 + s4*16 + quad*4 + r, q = l15 ----
    f32x4 st[4];
    __builtin_amdgcn_s_setprio(1);
#pragma unroll
    for (int s4 = 0; s4 < 4; ++s4) {
      const u16* kr = &Ks[buf][(s4 * 16 + l15) * 64];
      const bf16x8 kf0 = *(const bf16x8*)(kr + ((quad ^ swz) << 3));
      const bf16x8 kf1 = *(const bf16x8*)(kr + (((4 | quad) ^ swz) << 3));
      f32x4 a = {};
      a = __builtin_amdgcn_mfma_f32_16x16x32_bf16(kf0, qf0, a, 0, 0, 0);
      a = __builtin_amdgcn_mfma_f32_16x16x32_bf16(kf1, qf1, a, 0, 0, 0);
      st[s4] = a;
    }
    __builtin_amdgcn_s_setprio(0);

    // ---- softmax (scores already in log2 domain via pre-scaled Q) ----
    float s[16];
#pragma unroll
    for (int s4 = 0; s4 < 4; ++s4)
#pragma unroll
      for (int r = 0; r < 4; ++r) s[s4 * 4 + r] = st[s4][r];
    if (t == ntiles - 1) {  // diagonal tile: the only one needing the mask
#pragma unroll
      for (int s4 = 0; s4 < 4; ++s4)
#pragma unroll
        for (int r = 0; r < 4; ++r) {
          const int kv = n0 + s4 * 16 + quad * 4 + r;
          if (kv > m) s[s4 * 4 + r] = -INFINITY;
        }
    }
    float t8[8], t4[4];
#pragma unroll
    for (int i = 0; i < 8; ++i) t8[i] = fmaxf(s[i], s[i + 8]);
#pragma unroll
    for (int i = 0; i < 4; ++i) t4[i] = fmaxf(t8[i], t8[i + 4]);
    float mx = fmaxf(fmaxf(t4[0], t4[1]), fmaxf(t4[2], t4[3]));
    mx = fmaxf(mx, __shfl_xor(mx, 16));
    mx = fmaxf(mx, __shfl_xor(mx, 32));

    float mbase;
    if (__all(mx <= m_run + 8.0f)) {
      mbase = m_run;                     // defer: P bounded by 2^8, bf16-safe
    } else {
      mbase = fmaxf(m_run, mx);
      const float alpha = exp2f(m_run - mbase);  // 0 on first tile
      l_lane *= alpha;
#pragma unroll
      for (int dt = 0; dt < 4; ++dt) o[dt] *= alpha;
      m_run = mbase;
    }

    float p[16];
#pragma unroll
    for (int i = 0; i < 16; ++i) p[i] = exp2f(s[i] - mbase);
    float u8[8], u4[4];
#pragma unroll
    for (int i = 0; i < 8; ++i) u8[i] = p[i] + p[i + 8];
#pragma unroll
    for (int i = 0; i < 4; ++i) u4[i] = u8[i] + u8[i + 4];
    l_lane += (u4[0] + u4[1]) + (u4[2] + u4[3]);  // lane-local

    // ---- P -> LDS, stride 64 + chunk XOR swizzle; cvt_pk packing ----
#pragma unroll
    for (int s4 = 0; s4 < 4; ++s4) {
      u32 c0, c1;
      asm("v_cvt_pk_bf16_f32 %0, %1, %2"
          : "=v"(c0) : "v"(p[s4 * 4 + 0]), "v"(p[s4 * 4 + 1]));
      asm("v_cvt_pk_bf16_f32 %0, %1, %2"
          : "=v"(c1) : "v"(p[s4 * 4 + 2]), "v"(p[s4 * 4 + 3]));
      const int wchunk = ((s4 * 2 + (quad >> 1)) ^ swz) << 3;
      u32x2 w = { c0, c1 };
      *(u32x2*)&plds[l15 * 64 + wchunk + ((quad & 1) << 2)] = w;
    }
    asm volatile("s_waitcnt lgkmcnt(0)" ::: "memory");

    // ---- PV: o[dt] row = d = dt*16 + quad*4 + r, col = q = l15 ----
    __builtin_amdgcn_s_setprio(1);
#pragma unroll
    for (int ks = 0; ks < 2; ++ks) {
      const bf16x8 pf =
          *(const bf16x8*)&plds[l15 * 64 + (((ks * 4 + quad) ^ swz) << 3)];
#pragma unroll
      for (int dt = 0; dt < 4; ++dt) {
        const u16* vr = &Vs[buf][(dt * 16 + l15) * 64];
        const bf16x8 vf =
            *(const bf16x8*)(vr + ((((ks << 2) | quad) ^ swz) << 3));
        o[dt] = __builtin_amdgcn_mfma_f32_16x16x32_bf16(vf, pf, o[dt], 0, 0, 0);
      }
    }
    __builtin_amdgcn_s_setprio(0);

    __syncthreads();  // drains vmcnt(0): next tile staged; buf safe to reuse
    buf ^= 1;
  }

  float l = l_lane;
  l += __shfl_xor(l, 16);
  l += __shfl_xor(l, 32);
  const float inv = 1.0f / l;
  u16* crow = ctx + ((size_t)(b * 2048 + m) * 1024 + h * 64);
#pragma unroll
  for (int dt = 0; dt < 4; ++dt) {
    bf16x4 ov = { (short)f2b(o[dt][0] * inv), (short)f2b(o[dt][1] * inv),
                  (short)f2b(o[dt][2] * inv), (short)f2b(o[dt][3] * inv) };
    *(bf16x4*)&crow[dt * 16 + quad * 4] = ov;
  }
}

// ---------------------------------------------------------------------------
extern "C" void kernel_launch(void* const* d_in, const int* in_sizes, int n_in,
                              void* d_out, int out_size, void* d_ws,
                              size_t ws_size, hipStream_t stream) {
  // Interface (R9-verified): inputs fp32 in dict order, output fp32.
  const float* x  = (const float*)d_in[0];
  const float* wq = (const float*)d_in[1];
  const float* wk = (const float*)d_in[2];
  const float* wv = (const float*)d_in[3];
  const float* wo = (const float*)d_in[4];
  const float* bo = (const float*)d_in[5];
  float* out = (float*)d_out;

  // ws (bf16 elems): qb [0,4M) (aliased as ctx), kb [4M,8M), vt [8M,12M).
  // kb is dead after flash -> holds Wo in bf16 for gemm_out.
  u16* qb = (u16*)d_ws;
  u16* kb = qb + 4194304u;
  u16* vt = kb + 4194304u;
  u16* ctx = qb;
  u16* wob = kb;

  // d_out doubles as pre-converted-operand scratch until gemm_out runs:
  // xb [0, 8MiB) = x in bf16; wb [8, 14MiB) = Wq|Wk|Wv in bf16.
  u16* xb = (u16*)d_out;
  u16* wb = xb + 4194304u;

  convert_qw_kernel<<<3584, 256, 0, stream>>>(x, wq, wk, wv, xb, wb);
  gemm_qkv_kernel<<<dim3(32, 24), 256, 0, stream>>>(xb, wb, qb, kb, vt);
  flash_kernel<<<1024, 256, 0, stream>>>(qb, kb, vt, ctx);
  convert_wo_kernel<<<512, 256, 0, stream>>>(wo, wob);
  gemm_out_kernel<<<dim3(32, 16), 256, 0, stream>>>(ctx, wob, bo, out);
}